// Round 1
// baseline (338.764 us; speedup 1.0000x reference)
//
#include <hip/hip_runtime.h>
#include <math.h>

#define B_     8192
#define LATENT 32
#define CIN    128
#define HID    256
#define ACTD   16
#define NE     8
#define GH     128
#define IN0    160   // LATENT + CIN
#define INTER  288   // HID + LATENT

__device__ __forceinline__ float elu1(float x) {
    return x > 0.0f ? x : (expf(x) - 1.0f);
}

// -------- Kernel 1: LayerNorm(c) and X0 = concat([z, cn])  (one wave per row)
__global__ __launch_bounds__(256) void k_ln_concat(
    const float* __restrict__ z, const float* __restrict__ c,
    const float* __restrict__ g, const float* __restrict__ bt,
    float* __restrict__ X0)
{
    int gid  = blockIdx.x * 256 + threadIdx.x;
    int row  = gid >> 6;
    int lane = threadIdx.x & 63;
    if (row >= B_) return;
    const float* cr = c + (size_t)row * CIN;
    float v0 = cr[lane], v1 = cr[lane + 64];
    float s = v0 + v1;
    #pragma unroll
    for (int o = 32; o; o >>= 1) s += __shfl_xor(s, o);
    float mean = s * (1.0f / 128.0f);
    float d0 = v0 - mean, d1 = v1 - mean;
    float q = d0 * d0 + d1 * d1;
    #pragma unroll
    for (int o = 32; o; o >>= 1) q += __shfl_xor(q, o);
    float rstd = rsqrtf(q * (1.0f / 128.0f) + 1e-5f);
    float* xr = X0 + (size_t)row * IN0;
    xr[LATENT + lane]      = d0 * rstd * g[lane]      + bt[lane];
    xr[LATENT + lane + 64] = d1 * rstd * g[lane + 64] + bt[lane + 64];
    if (lane < LATENT) xr[lane] = z[(size_t)row * LATENT + lane];
}

// -------- Kernel 2: plain tiled GEMM + bias + ELU (gate layers 0 and 1)
// out[r, o] = elu( sum_k A[r,k]*W[k,o] + bias[o] ),  64x64 tile, BK=32
__global__ __launch_bounds__(256) void k_gate_gemm(
    const float* __restrict__ A, int lda, int K,
    const float* __restrict__ W, int ldw,
    const float* __restrict__ bias,
    float* __restrict__ out, int ldo)
{
    __shared__ float As[32][68];   // [k][m]
    __shared__ float Bs[32][68];   // [k][n]
    int tid  = threadIdx.x;
    int brow = blockIdx.y * 64;
    int bn   = blockIdx.x * 64;
    int tx = tid & 15, ty = tid >> 4;
    int lm = tid >> 3, lk = (tid & 7) << 2;
    int wk = tid >> 4, wn = (tid & 15) << 2;
    float acc[4][4] = {};
    for (int k0 = 0; k0 < K; k0 += 32) {
        #pragma unroll
        for (int h = 0; h < 2; ++h) {
            int m = lm + (h << 5);
            float4 v = *(const float4*)(A + (size_t)(brow + m) * lda + k0 + lk);
            As[lk + 0][m] = v.x; As[lk + 1][m] = v.y;
            As[lk + 2][m] = v.z; As[lk + 3][m] = v.w;
        }
        #pragma unroll
        for (int h = 0; h < 2; ++h) {
            int k = wk + (h << 4);
            *(float4*)&Bs[k][wn] = *(const float4*)(W + (size_t)(k0 + k) * ldw + bn + wn);
        }
        __syncthreads();
        #pragma unroll
        for (int kk = 0; kk < 32; ++kk) {
            float av[4], bv[4];
            *(float4*)av = *(const float4*)&As[kk][ty << 2];
            *(float4*)bv = *(const float4*)&Bs[kk][tx << 2];
            #pragma unroll
            for (int i = 0; i < 4; ++i)
                #pragma unroll
                for (int j = 0; j < 4; ++j)
                    acc[i][j] = fmaf(av[i], bv[j], acc[i][j]);
        }
        __syncthreads();
    }
    #pragma unroll
    for (int i = 0; i < 4; ++i) {
        int r  = brow + (ty << 2) + i;
        int o0 = bn + (tx << 2);
        float4 ov;
        ov.x = elu1(acc[i][0] + bias[o0 + 0]);
        ov.y = elu1(acc[i][1] + bias[o0 + 1]);
        ov.z = elu1(acc[i][2] + bias[o0 + 2]);
        ov.w = elu1(acc[i][3] + bias[o0 + 3]);
        *(float4*)(out + (size_t)r * ldo + o0) = ov;
    }
}

// -------- Kernel 3: gate output layer + softmax over 8 experts (one wave/row)
__global__ __launch_bounds__(256) void k_gate_out(
    const float* __restrict__ G2, const float* __restrict__ g2w,
    const float* __restrict__ g2b, float* __restrict__ coeff)
{
    __shared__ float wt[NE][GH];   // transposed g2w
    int tid = threadIdx.x;
    for (int idx = tid; idx < GH * NE; idx += 256) {
        int k = idx >> 3, e = idx & 7;
        wt[e][k] = g2w[idx];
    }
    __syncthreads();
    int row  = (blockIdx.x * 256 + tid) >> 6;
    int lane = tid & 63;
    if (row >= B_) return;
    float a0 = G2[(size_t)row * GH + lane];
    float a1 = G2[(size_t)row * GH + 64 + lane];
    float p[NE];
    #pragma unroll
    for (int e = 0; e < NE; ++e)
        p[e] = a0 * wt[e][lane] + a1 * wt[e][lane + 64];
    #pragma unroll
    for (int o = 32; o; o >>= 1) {
        #pragma unroll
        for (int e = 0; e < NE; ++e) p[e] += __shfl_xor(p[e], o);
    }
    float mx = -1e30f;
    #pragma unroll
    for (int e = 0; e < NE; ++e) { p[e] += g2b[e]; mx = fmaxf(mx, p[e]); }
    float s = 0.0f;
    #pragma unroll
    for (int e = 0; e < NE; ++e) { p[e] = expf(p[e] - mx); s += p[e]; }
    float inv = 1.0f / s;
    if (lane == 0) {
        #pragma unroll
        for (int e = 0; e < NE; ++e) coeff[(size_t)row * NE + e] = p[e] * inv;
    }
}

// -------- Kernel 4: MoE layer as single GEMM with coeff-scaled concat A.
// A[b, e*I+i] = coeff[b,e] * (i<32 ? z[b,i] : feat[b,i-32]); W flat [E*I, 256].
__global__ __launch_bounds__(256) void k_moe_gemm(
    const float* __restrict__ X0, const float* __restrict__ F, int fstride,
    const float* __restrict__ coeff, const float* __restrict__ W,
    const float* __restrict__ bias, float* __restrict__ out,
    int I, int doElu)
{
    __shared__ float As[32][68];
    __shared__ float Bs[32][68];
    __shared__ float cfs[64][8];
    int tid  = threadIdx.x;
    int brow = blockIdx.y * 64;
    int bn   = blockIdx.x * 64;
    for (int idx = tid; idx < 512; idx += 256)
        cfs[idx >> 3][idx & 7] = coeff[(size_t)brow * 8 + idx];
    __syncthreads();
    int tx = tid & 15, ty = tid >> 4;
    int lm = tid >> 3, lk = (tid & 7) << 2;
    int wk = tid >> 4, wn = (tid & 15) << 2;
    float acc[4][4] = {};
    for (int e = 0; e < NE; ++e) {
        const float* We = W + (size_t)e * I * HID;
        for (int k0 = 0; k0 < I; k0 += 32) {
            #pragma unroll
            for (int h = 0; h < 2; ++h) {
                int m = lm + (h << 5);
                int R = brow + m;
                int i = k0 + lk;
                const float* src = (i < LATENT)
                    ? (X0 + (size_t)R * IN0 + i)
                    : (F + (size_t)R * fstride + (i - LATENT));
                float4 v = *(const float4*)src;
                float sc = cfs[m][e];
                As[lk + 0][m] = v.x * sc; As[lk + 1][m] = v.y * sc;
                As[lk + 2][m] = v.z * sc; As[lk + 3][m] = v.w * sc;
            }
            #pragma unroll
            for (int h = 0; h < 2; ++h) {
                int k = wk + (h << 4);
                *(float4*)&Bs[k][wn] = *(const float4*)(We + (size_t)(k0 + k) * HID + bn + wn);
            }
            __syncthreads();
            #pragma unroll
            for (int kk = 0; kk < 32; ++kk) {
                float av[4], bv[4];
                *(float4*)av = *(const float4*)&As[kk][ty << 2];
                *(float4*)bv = *(const float4*)&Bs[kk][tx << 2];
                #pragma unroll
                for (int i = 0; i < 4; ++i)
                    #pragma unroll
                    for (int j = 0; j < 4; ++j)
                        acc[i][j] = fmaf(av[i], bv[j], acc[i][j]);
            }
            __syncthreads();
        }
    }
    #pragma unroll
    for (int i = 0; i < 4; ++i) {
        int r  = brow + (ty << 2) + i;
        int o0 = bn + (tx << 2);
        float bsum[4] = {0.f, 0.f, 0.f, 0.f};
        #pragma unroll
        for (int e = 0; e < NE; ++e) {
            float cf = cfs[(ty << 2) + i][e];
            #pragma unroll
            for (int j = 0; j < 4; ++j)
                bsum[j] = fmaf(cf, bias[e * HID + o0 + j], bsum[j]);
        }
        float4 ov;
        float r0 = acc[i][0] + bsum[0];
        float r1 = acc[i][1] + bsum[1];
        float r2 = acc[i][2] + bsum[2];
        float r3 = acc[i][3] + bsum[3];
        if (doElu) { r0 = elu1(r0); r1 = elu1(r1); r2 = elu1(r2); r3 = elu1(r3); }
        ov.x = r0; ov.y = r1; ov.z = r2; ov.w = r3;
        *(float4*)(out + (size_t)r * HID + o0) = ov;
    }
}

// -------- Kernel 5: MoE final layer, N=16, no activation
__global__ __launch_bounds__(256) void k_moe_gemm_n16(
    const float* __restrict__ X0, const float* __restrict__ F, int fstride,
    const float* __restrict__ coeff, const float* __restrict__ W,
    const float* __restrict__ bias, float* __restrict__ out, int I)
{
    __shared__ float As[32][68];
    __shared__ float Bs[32][20];
    __shared__ float cfs[64][8];
    int tid  = threadIdx.x;
    int brow = blockIdx.x * 64;
    for (int idx = tid; idx < 512; idx += 256)
        cfs[idx >> 3][idx & 7] = coeff[(size_t)brow * 8 + idx];
    __syncthreads();
    int ty = tid >> 2, tx = tid & 3;
    int lm = tid >> 3, lk = (tid & 7) << 2;
    float acc[4] = {};
    for (int e = 0; e < NE; ++e) {
        const float* We = W + (size_t)e * I * ACTD;
        for (int k0 = 0; k0 < I; k0 += 32) {
            #pragma unroll
            for (int h = 0; h < 2; ++h) {
                int m = lm + (h << 5);
                int R = brow + m;
                int i = k0 + lk;
                const float* src = (i < LATENT)
                    ? (X0 + (size_t)R * IN0 + i)
                    : (F + (size_t)R * fstride + (i - LATENT));
                float4 v = *(const float4*)src;
                float sc = cfs[m][e];
                As[lk + 0][m] = v.x * sc; As[lk + 1][m] = v.y * sc;
                As[lk + 2][m] = v.z * sc; As[lk + 3][m] = v.w * sc;
            }
            if (tid < 128) {
                int k = tid >> 2, n4 = (tid & 3) << 2;
                *(float4*)&Bs[k][n4] = *(const float4*)(We + (size_t)(k0 + k) * ACTD + n4);
            }
            __syncthreads();
            #pragma unroll
            for (int kk = 0; kk < 32; ++kk) {
                float a = As[kk][ty];
                float bv[4];
                *(float4*)bv = *(const float4*)&Bs[kk][tx << 2];
                #pragma unroll
                for (int j = 0; j < 4; ++j) acc[j] = fmaf(a, bv[j], acc[j]);
            }
            __syncthreads();
        }
    }
    int r = brow + ty;
    float bs[4] = {0.f, 0.f, 0.f, 0.f};
    #pragma unroll
    for (int e = 0; e < NE; ++e) {
        float cf = cfs[ty][e];
        #pragma unroll
        for (int j = 0; j < 4; ++j)
            bs[j] = fmaf(cf, bias[e * ACTD + (tx << 2) + j], bs[j]);
    }
    float4 ov;
    ov.x = acc[0] + bs[0]; ov.y = acc[1] + bs[1];
    ov.z = acc[2] + bs[2]; ov.w = acc[3] + bs[3];
    *(float4*)(out + (size_t)r * ACTD + (tx << 2)) = ov;
}

extern "C" void kernel_launch(void* const* d_in, const int* in_sizes, int n_in,
                              void* d_out, int out_size, void* d_ws, size_t ws_size,
                              hipStream_t stream)
{
    (void)in_sizes; (void)n_in; (void)out_size; (void)ws_size;
    const float* z   = (const float*)d_in[0];
    const float* c   = (const float*)d_in[1];
    const float* w0  = (const float*)d_in[2];
    const float* b0  = (const float*)d_in[3];
    const float* w1  = (const float*)d_in[4];
    const float* b1  = (const float*)d_in[5];
    const float* w2  = (const float*)d_in[6];
    const float* b2  = (const float*)d_in[7];
    const float* g0w = (const float*)d_in[8];
    const float* g0b = (const float*)d_in[9];
    const float* g1w = (const float*)d_in[10];
    const float* g1b = (const float*)d_in[11];
    const float* g2w = (const float*)d_in[12];
    const float* g2b = (const float*)d_in[13];
    const float* lng = (const float*)d_in[14];
    const float* lnb = (const float*)d_in[15];
    float* out = (float*)d_out;

    float* X0 = (float*)d_ws;                  // [B,160]
    float* H1 = X0 + (size_t)B_ * IN0;         // [B,256] (gate G1 aliases here)
    float* H2 = H1 + (size_t)B_ * HID;         // [B,256] (gate G2 aliases here)
    float* cf = H2 + (size_t)B_ * HID;         // [B,8]

    k_ln_concat<<<dim3(B_ / 4), dim3(256), 0, stream>>>(z, c, lng, lnb, X0);
    // gate MLP: X0 -> G1(H1) -> G2(H2) -> coeff
    k_gate_gemm<<<dim3(2, 128), dim3(256), 0, stream>>>(X0, IN0, IN0, g0w, GH, g0b, H1, GH);
    k_gate_gemm<<<dim3(2, 128), dim3(256), 0, stream>>>(H1, GH, GH, g1w, GH, g1b, H2, GH);
    k_gate_out<<<dim3(B_ / 4), dim3(256), 0, stream>>>(H2, g2w, g2b, cf);
    // expert layers as single scaled-A GEMMs
    k_moe_gemm<<<dim3(4, 128), dim3(256), 0, stream>>>(X0, X0 + LATENT, IN0, cf, w0, b0, H1, IN0, 1);
    k_moe_gemm<<<dim3(4, 128), dim3(256), 0, stream>>>(X0, H1, HID, cf, w1, b1, H2, INTER, 1);
    k_moe_gemm_n16<<<dim3(128), dim3(256), 0, stream>>>(X0, H2, HID, cf, w2, b2, out, INTER);
}

// Round 2
// 133.274 us; speedup vs baseline: 2.5419x; 2.5419x over previous
//
#include <hip/hip_runtime.h>
#include <hip/hip_bf16.h>
#include <math.h>

#define B_     8192
#define LATENT 32
#define CIN    128
#define HID    256
#define ACTD   16
#define NE     8
#define GH     128
#define IN0    160   // LATENT + CIN
#define INTER  288   // HID + LATENT

typedef __attribute__((ext_vector_type(8))) short short8;
typedef __attribute__((ext_vector_type(4))) float f32x4;

__device__ __forceinline__ float elu1(float x) { return x > 0.0f ? x : expm1f(x); }

__device__ __forceinline__ unsigned short bfh(float v) {
    __hip_bfloat16 b = __float2bfloat16(v);
    return *reinterpret_cast<unsigned short*>(&b);
}
__device__ __forceinline__ float bf2f(unsigned short u) {
    __hip_bfloat16 b;
    *reinterpret_cast<unsigned short*>(&b) = u;
    return __bfloat162float(b);
}
__device__ __forceinline__ void gload16(const unsigned short* g, unsigned short* lds) {
    __builtin_amdgcn_global_load_lds((const __attribute__((address_space(1))) void*)g,
                                     (__attribute__((address_space(3))) void*)lds, 16, 0, 0);
}

// ---------- prep: transpose + hi/lo split all weight matrices ----------
// w0 [8][160][256] -> T0 [8][256][160]; w1 [8][288][256] -> T1 [8][256][288]
// w2 [8][288][16]  -> T2 [128][288];   g0w [160][128] -> G0T [128][160]
// g1w [128][128] -> G1T [128][128]
__global__ __launch_bounds__(256) void k_prep(
    const float* __restrict__ w0, const float* __restrict__ w1, const float* __restrict__ w2,
    const float* __restrict__ g0w, const float* __restrict__ g1w,
    unsigned short* __restrict__ T0h, unsigned short* __restrict__ T0l,
    unsigned short* __restrict__ T1h, unsigned short* __restrict__ T1l,
    unsigned short* __restrict__ T2h, unsigned short* __restrict__ T2l,
    unsigned short* __restrict__ G0h, unsigned short* __restrict__ G0l,
    unsigned short* __restrict__ G1h, unsigned short* __restrict__ G1l)
{
    int id = blockIdx.x * 256 + threadIdx.x;
    float v; size_t dst; unsigned short *H, *L;
    if (id < 327680) {
        int o = id & 255, ei = id >> 8, i = ei % 160, e = ei / 160;
        v = w0[id]; H = T0h; L = T0l; dst = (size_t)(e * 256 + o) * 160 + i;
    } else if (id < 917504) {
        int t = id - 327680;
        int o = t & 255, ei = t >> 8, i = ei % 288, e = ei / 288;
        v = w1[t]; H = T1h; L = T1l; dst = (size_t)(e * 256 + o) * 288 + i;
    } else if (id < 954368) {
        int t = id - 917504;
        int o = t & 15, ei = t >> 4, i = ei % 288, e = ei / 288;
        v = w2[t]; H = T2h; L = T2l; dst = (size_t)(e * 16 + o) * 288 + i;
    } else if (id < 974848) {
        int t = id - 954368;
        int o = t & 127, i = t >> 7;
        v = g0w[t]; H = G0h; L = G0l; dst = (size_t)o * 160 + i;
    } else if (id < 991232) {
        int t = id - 974848;
        int o = t & 127, i = t >> 7;
        v = g1w[t]; H = G1h; L = G1l; dst = (size_t)o * 128 + i;
    } else return;
    unsigned short h = bfh(v);
    unsigned short lo = bfh(v - bf2f(h));
    H[dst] = h; L[dst] = lo;
}

// ---------- LayerNorm + concat, split to hi/lo; also seed z into X1/X2 ----------
__global__ __launch_bounds__(256) void k_ln_concat2(
    const float* __restrict__ z, const float* __restrict__ c,
    const float* __restrict__ g, const float* __restrict__ bt,
    unsigned short* __restrict__ X0h, unsigned short* __restrict__ X0l,
    unsigned short* __restrict__ X1h, unsigned short* __restrict__ X1l,
    unsigned short* __restrict__ X2h, unsigned short* __restrict__ X2l)
{
    int gid = blockIdx.x * 256 + threadIdx.x;
    int row = gid >> 6;
    int l = threadIdx.x & 63;
    if (row >= B_) return;
    const float* cr = c + (size_t)row * CIN;
    float v0 = cr[l], v1 = cr[l + 64];
    float s = v0 + v1;
    #pragma unroll
    for (int o = 32; o; o >>= 1) s += __shfl_xor(s, o);
    float mean = s * (1.0f / 128.0f);
    float d0 = v0 - mean, d1 = v1 - mean;
    float q = d0 * d0 + d1 * d1;
    #pragma unroll
    for (int o = 32; o; o >>= 1) q += __shfl_xor(q, o);
    float rstd = rsqrtf(q * (1.0f / 128.0f) + 1e-5f);
    float y0 = d0 * rstd * g[l] + bt[l];
    float y1 = d1 * rstd * g[l + 64] + bt[l + 64];
    size_t r0 = (size_t)row * IN0;
    unsigned short h0 = bfh(y0), lo0 = bfh(y0 - bf2f(h0));
    unsigned short h1 = bfh(y1), lo1 = bfh(y1 - bf2f(h1));
    X0h[r0 + 32 + l] = h0; X0l[r0 + 32 + l] = lo0;
    X0h[r0 + 96 + l] = h1; X0l[r0 + 96 + l] = lo1;
    if (l < LATENT) {
        float zv = z[(size_t)row * LATENT + l];
        unsigned short zh = bfh(zv), zl = bfh(zv - bf2f(zh));
        X0h[r0 + l] = zh; X0l[r0 + l] = zl;
        size_t r1 = (size_t)row * INTER;
        X1h[r1 + l] = zh; X1l[r1 + l] = zl;
        X2h[r1 + l] = zh; X2l[r1 + l] = zl;
    }
}

// ---------- generic hi/lo-split bf16 MFMA GEMM ----------
// C[row,col] (128x64 block tile) = sum over (e,k) of A[row,k]*B[e][col,k]
// A: [M][I_] hi/lo bf16 (shared across e). B: [NE_T*N_][I_] transposed hi/lo.
// NE_T>1: per-e acc init'd with bias[e], folded by coeff into total.
// OUTM: 0 = fp32 raw; 1 = ELU + hi/lo bf16 split; 2 = fp32 + ELU.
template<int I_, int N_, int NE_T, int OUTM, int SOUT, int OFS>
__global__ __launch_bounds__(256) void k_mfma_gemm(
    const unsigned short* __restrict__ Ah, const unsigned short* __restrict__ Al,
    const unsigned short* __restrict__ Bh, const unsigned short* __restrict__ Bl,
    const float* __restrict__ bias, const float* __restrict__ coeff,
    float* __restrict__ outF, unsigned short* __restrict__ outH,
    unsigned short* __restrict__ outL)
{
    constexpr int KS = I_ / 32;
    __shared__ unsigned short smem[2][12288];   // per buf: Ah 4096, Al 4096, Bh 2048, Bl 2048 shorts
    __shared__ float cf_s[8][128];
    __shared__ float bias_s[8][64];

    const int tid = threadIdx.x, wid = tid >> 6, l = tid & 63;
    const int wm = wid >> 1, wn = wid & 1;
    const int brow = blockIdx.y * 128, bn = blockIdx.x * 64;

    if (NE_T > 1) {
        for (int idx = tid; idx < 1024; idx += 256)
            cf_s[idx & 7][idx >> 3] = coeff[(size_t)(brow + (idx >> 3)) * 8 + (idx & 7)];
    }
    for (int idx = tid; idx < NE_T * 64; idx += 256)
        bias_s[idx >> 6][idx & 63] = bias[(idx >> 6) * N_ + bn + (idx & 63)];

    // staging: linear LDS dest, inverse-swizzled global source (swz: slot ^= (row>>1)&3)
    const int a_off  = (l >> 2) * I_ + (((l & 3) ^ ((l >> 3) & 3)) << 3);      // elements
    // frag read: row = base+(l&15), k-slot = l>>4, swizzled
    const int rd_off = ((l & 15) << 5) + (((l >> 4) ^ ((l >> 1) & 3)) << 3);   // shorts

    const unsigned short* Abh = Ah + (size_t)brow * I_;
    const unsigned short* Abl = Al + (size_t)brow * I_;

    int se = 0, sk = 0, cur = 0;
    auto stage = [&](int bi) {
        unsigned short* buf = smem[bi];
        const int k0 = sk * 32;
        const unsigned short* ah = Abh + k0 + a_off;
        const unsigned short* al = Abl + k0 + a_off;
        const size_t bofs = (size_t)(se * N_ + bn) * I_ + k0 + a_off;
        const unsigned short* bh = Bh + bofs;
        const unsigned short* bl = Bl + bofs;
        gload16(ah + wid * 16 * I_,       buf + wid * 512);
        gload16(ah + (wid + 4) * 16 * I_, buf + (wid + 4) * 512);
        gload16(al + wid * 16 * I_,       buf + 4096 + wid * 512);
        gload16(al + (wid + 4) * 16 * I_, buf + 4096 + (wid + 4) * 512);
        gload16(bh + wid * 16 * I_,       buf + 8192 + wid * 512);
        gload16(bl + wid * 16 * I_,       buf + 10240 + wid * 512);
        if (++sk == KS) { sk = 0; ++se; }
    };

    f32x4 accT[4][2];
    f32x4 accW[4][2];
    const f32x4 z4 = {0.f, 0.f, 0.f, 0.f};
    if (NE_T > 1) {
        #pragma unroll
        for (int mf = 0; mf < 4; ++mf)
            #pragma unroll
            for (int nf = 0; nf < 2; ++nf) accT[mf][nf] = z4;
    }

    stage(0);
    __syncthreads();   // drains prologue stage + cf/bias LDS writes (once per block)

    for (int e = 0; e < NE_T; ++e) {
        #pragma unroll
        for (int nf = 0; nf < 2; ++nf) {
            float bv = bias_s[NE_T > 1 ? e : 0][wn * 32 + nf * 16 + (l & 15)];
            f32x4 bv4 = {bv, bv, bv, bv};
            #pragma unroll
            for (int mf = 0; mf < 4; ++mf) accW[mf][nf] = bv4;
        }
        for (int ks = 0; ks < KS; ++ks) {
            if (se < NE_T) {
                stage(cur ^ 1);
                asm volatile("s_waitcnt vmcnt(6)" ::: "memory");
            } else {
                asm volatile("s_waitcnt vmcnt(0)" ::: "memory");
            }
            __builtin_amdgcn_s_barrier();
            asm volatile("" ::: "memory");
            const unsigned short* bp = smem[cur];
            short8 afh[4], afl[4], bqh[2], bql[2];
            #pragma unroll
            for (int mf = 0; mf < 4; ++mf) {
                const int ro = (wm * 64 + mf * 16) * 32;
                afh[mf] = *(const short8*)(bp + ro + rd_off);
                afl[mf] = *(const short8*)(bp + 4096 + ro + rd_off);
            }
            #pragma unroll
            for (int nf = 0; nf < 2; ++nf) {
                const int ro = (wn * 32 + nf * 16) * 32;
                bqh[nf] = *(const short8*)(bp + 8192 + ro + rd_off);
                bql[nf] = *(const short8*)(bp + 10240 + ro + rd_off);
            }
            #pragma unroll
            for (int mf = 0; mf < 4; ++mf)
                #pragma unroll
                for (int nf = 0; nf < 2; ++nf) {
                    accW[mf][nf] = __builtin_amdgcn_mfma_f32_16x16x32_bf16(afh[mf], bqh[nf], accW[mf][nf], 0, 0, 0);
                    accW[mf][nf] = __builtin_amdgcn_mfma_f32_16x16x32_bf16(afh[mf], bql[nf], accW[mf][nf], 0, 0, 0);
                    accW[mf][nf] = __builtin_amdgcn_mfma_f32_16x16x32_bf16(afl[mf], bqh[nf], accW[mf][nf], 0, 0, 0);
                }
            asm volatile("s_waitcnt lgkmcnt(0)" ::: "memory");
            __builtin_amdgcn_s_barrier();
            asm volatile("" ::: "memory");
            cur ^= 1;
        }
        if (NE_T > 1) {
            #pragma unroll
            for (int mf = 0; mf < 4; ++mf) {
                f32x4 cv = *(const f32x4*)&cf_s[e][wm * 64 + mf * 16 + ((l >> 4) << 2)];
                #pragma unroll
                for (int nf = 0; nf < 2; ++nf)
                    #pragma unroll
                    for (int r = 0; r < 4; ++r)
                        accT[mf][nf][r] += cv[r] * accW[mf][nf][r];
            }
        }
    }

    #pragma unroll
    for (int mf = 0; mf < 4; ++mf)
        #pragma unroll
        for (int nf = 0; nf < 2; ++nf)
            #pragma unroll
            for (int r = 0; r < 4; ++r) {
                float v = (NE_T > 1) ? accT[mf][nf][r] : accW[mf][nf][r];
                const int row = brow + wm * 64 + mf * 16 + ((l >> 4) << 2) + r;
                const int col = bn + wn * 32 + nf * 16 + (l & 15);
                size_t o = (size_t)row * SOUT + OFS + col;
                if (OUTM == 0) {
                    outF[o] = v;
                } else if (OUTM == 2) {
                    outF[o] = elu1(v);
                } else {
                    float ev = elu1(v);
                    unsigned short h = bfh(ev);
                    unsigned short lo = bfh(ev - bf2f(h));
                    outH[o] = h; outL[o] = lo;
                }
            }
}

// ---------- gate output layer + softmax over 8 experts (one wave/row) ----------
__global__ __launch_bounds__(256) void k_gate_out(
    const float* __restrict__ G2, const float* __restrict__ g2w,
    const float* __restrict__ g2b, float* __restrict__ coeff)
{
    __shared__ float wt[NE][GH];
    int tid = threadIdx.x;
    for (int idx = tid; idx < GH * NE; idx += 256) {
        int k = idx >> 3, e = idx & 7;
        wt[e][k] = g2w[idx];
    }
    __syncthreads();
    int row  = (blockIdx.x * 256 + tid) >> 6;
    int lane = tid & 63;
    if (row >= B_) return;
    float a0 = G2[(size_t)row * GH + lane];
    float a1 = G2[(size_t)row * GH + 64 + lane];
    float p[NE];
    #pragma unroll
    for (int e = 0; e < NE; ++e)
        p[e] = a0 * wt[e][lane] + a1 * wt[e][lane + 64];
    #pragma unroll
    for (int o = 32; o; o >>= 1) {
        #pragma unroll
        for (int e = 0; e < NE; ++e) p[e] += __shfl_xor(p[e], o);
    }
    float mx = -1e30f;
    #pragma unroll
    for (int e = 0; e < NE; ++e) { p[e] += g2b[e]; mx = fmaxf(mx, p[e]); }
    float s = 0.0f;
    #pragma unroll
    for (int e = 0; e < NE; ++e) { p[e] = expf(p[e] - mx); s += p[e]; }
    float inv = 1.0f / s;
    if (lane == 0) {
        #pragma unroll
        for (int e = 0; e < NE; ++e) coeff[(size_t)row * NE + e] = p[e] * inv;
    }
}

// ---------- final mix: out[b,o] = sum_e cf[b,e] * P[b, e*16+o] ----------
__global__ __launch_bounds__(256) void k_mix(
    const float* __restrict__ P, const float* __restrict__ cf, float* __restrict__ out)
{
    int id = blockIdx.x * 256 + threadIdx.x;
    if (id >= B_ * ACTD) return;
    int b = id >> 4, o = id & 15;
    const float* pr = P + (size_t)b * 128 + o;
    const float* cr = cf + (size_t)b * 8;
    float s = 0.f;
    #pragma unroll
    for (int e = 0; e < 8; ++e) s += cr[e] * pr[e * 16];
    out[id] = s;
}

extern "C" void kernel_launch(void* const* d_in, const int* in_sizes, int n_in,
                              void* d_out, int out_size, void* d_ws, size_t ws_size,
                              hipStream_t stream)
{
    (void)in_sizes; (void)n_in; (void)out_size; (void)ws_size;
    const float* z   = (const float*)d_in[0];
    const float* c   = (const float*)d_in[1];
    const float* w0  = (const float*)d_in[2];
    const float* b0  = (const float*)d_in[3];
    const float* w1  = (const float*)d_in[4];
    const float* b1  = (const float*)d_in[5];
    const float* w2  = (const float*)d_in[6];
    const float* b2  = (const float*)d_in[7];
    const float* g0w = (const float*)d_in[8];
    const float* g0b = (const float*)d_in[9];
    const float* g1w = (const float*)d_in[10];
    const float* g1b = (const float*)d_in[11];
    const float* g2w = (const float*)d_in[12];
    const float* g2b = (const float*)d_in[13];
    const float* lng = (const float*)d_in[14];
    const float* lnb = (const float*)d_in[15];
    float* out = (float*)d_out;

    char* p = (char*)d_ws;
    auto alloc = [&](size_t n) { char* r = p; p += (n + 255) & ~(size_t)255; return r; };
    unsigned short* X0h = (unsigned short*)alloc((size_t)B_ * IN0 * 2);
    unsigned short* X0l = (unsigned short*)alloc((size_t)B_ * IN0 * 2);
    unsigned short* X1h = (unsigned short*)alloc((size_t)B_ * INTER * 2);
    unsigned short* X1l = (unsigned short*)alloc((size_t)B_ * INTER * 2);
    unsigned short* X2h = (unsigned short*)alloc((size_t)B_ * INTER * 2);
    unsigned short* X2l = (unsigned short*)alloc((size_t)B_ * INTER * 2);
    unsigned short* G1h = (unsigned short*)alloc((size_t)B_ * GH * 2);
    unsigned short* G1l = (unsigned short*)alloc((size_t)B_ * GH * 2);
    float* G2f = (float*)alloc((size_t)B_ * GH * 4);      // also reused as P2 (after gate_out)
    float* cf  = (float*)alloc((size_t)B_ * NE * 4);
    unsigned short* T0h = (unsigned short*)alloc((size_t)NE * IN0 * HID * 2);
    unsigned short* T0l = (unsigned short*)alloc((size_t)NE * IN0 * HID * 2);
    unsigned short* T1h = (unsigned short*)alloc((size_t)NE * INTER * HID * 2);
    unsigned short* T1l = (unsigned short*)alloc((size_t)NE * INTER * HID * 2);
    unsigned short* T2h = (unsigned short*)alloc((size_t)NE * INTER * ACTD * 2);
    unsigned short* T2l = (unsigned short*)alloc((size_t)NE * INTER * ACTD * 2);
    unsigned short* G0Th = (unsigned short*)alloc((size_t)IN0 * GH * 2);
    unsigned short* G0Tl = (unsigned short*)alloc((size_t)IN0 * GH * 2);
    unsigned short* G1Th = (unsigned short*)alloc((size_t)GH * GH * 2);
    unsigned short* G1Tl = (unsigned short*)alloc((size_t)GH * GH * 2);
    float* P2 = G2f;

    k_prep<<<dim3(3872), dim3(256), 0, stream>>>(w0, w1, w2, g0w, g1w,
        T0h, T0l, T1h, T1l, T2h, T2l, G0Th, G0Tl, G1Th, G1Tl);
    k_ln_concat2<<<dim3(B_ / 4), dim3(256), 0, stream>>>(z, c, lng, lnb,
        X0h, X0l, X1h, X1l, X2h, X2l);

    // gate MLP
    k_mfma_gemm<160, 128, 1, 1, 128, 0><<<dim3(2, 64), dim3(256), 0, stream>>>(
        X0h, X0l, G0Th, G0Tl, g0b, nullptr, nullptr, G1h, G1l);
    k_mfma_gemm<128, 128, 1, 2, 128, 0><<<dim3(2, 64), dim3(256), 0, stream>>>(
        G1h, G1l, G1Th, G1Tl, g1b, nullptr, G2f, nullptr, nullptr);
    k_gate_out<<<dim3(B_ / 4), dim3(256), 0, stream>>>(G2f, g2w, g2b, cf);

    // expert layers
    k_mfma_gemm<160, 256, 8, 1, 288, 32><<<dim3(4, 64), dim3(256), 0, stream>>>(
        X0h, X0l, T0h, T0l, b0, cf, nullptr, X1h, X1l);
    k_mfma_gemm<288, 256, 8, 1, 288, 32><<<dim3(4, 64), dim3(256), 0, stream>>>(
        X1h, X1l, T1h, T1l, b1, cf, nullptr, X2h, X2l);
    // final layer as plain GEMM over N = E*16 = 128, then coeff-mix
    k_mfma_gemm<288, 128, 1, 0, 128, 0><<<dim3(2, 64), dim3(256), 0, stream>>>(
        X2h, X2l, T2h, T2l, b2, nullptr, P2, nullptr, nullptr);
    k_mix<<<dim3(B_ * ACTD / 256), dim3(256), 0, stream>>>(P2, cf, out);
}